// Round 4
// baseline (946.291 us; speedup 1.0000x reference)
//
#include <hip/hip_runtime.h>
#include <math.h>

// B=64, C=512, S=512, E=257, LK=128, HK=129.
// high_x is dead code in the reference: only low_x = attn(low,low,low)+attn(low,high,low).
//
// Pipeline (all heavy math on MFMA f16):
//  1. build_W: Wt[c][n] f16 = combined rfft+projection weight (512 -> 1028), B-transposed
//  2. build_idt: iDt[n][k] f16 = irfft matrix matching OXh row layout [re264|im264]
//  3. gemm_main (MFMA f16): LHf = relu(x @ W + bias) * S_FOLD, f16 rows [lr|li|hr|hi] (264 pad)
//  4. repack_K: LHf -> Kpack in exact MFMA B-frag order (coalesced attention loads)
//  5. repack_V: LHf low -> Vpack (LDS transpose) in PV B-frag order
//  6. attn (MFMA f16 flash, DEFERRED PV): Q in regs, P in lane-contiguous LDS layout
//     (conflict-free PV reads), 3 blocks/CU via __launch_bounds__(256,3) + 40KB LDS.
//  7. gemm_irfft (MFMA f16): out = OXh @ iDt
//
// ws: LHf 69.2 MB + Kpack 75.5 MB + Vpack 35.7 MB + Wt 1.1 MB + iDt 0.6 MB ~= 182 MB.

#define LD16 1056   // halves per LHf row: [lr 264 | li 264 | hr 264 | hi 264]
#define OXOFF 528   // OXh f16 output written into LHf[row][528..1056): [re 264 | im 264]

typedef __attribute__((ext_vector_type(4))) _Float16 f16x4;
typedef __attribute__((ext_vector_type(8))) _Float16 f16x8;
typedef __attribute__((ext_vector_type(4))) float f32x4;

#define S_FOLD 0.24975653f    // sqrt(1/sqrt(257))
#define INV_S  4.0039005f     // 1/S_FOLD
#define SC512  0.0441941738241592f   // 1/sqrt(512)

// ---------------- build combined rfft+projection weight, B-transposed ----------------
// Wt[c][n], c in [0,1088), n in [0,512). c>=1028 -> 0.
// c<257: low_r; 257..513: low_i; 514..770: high_r; 771..1027: high_i.

__global__ __launch_bounds__(256) void build_W(
    const float* __restrict__ l1r, const float* __restrict__ l1i,
    const float* __restrict__ h1r, const float* __restrict__ h1i,
    _Float16* __restrict__ Wt) {
  int c = blockIdx.x;
  int t = threadIdx.x;
  if (c >= 1028) {
    for (int n = t; n < 512; n += 256) Wt[(size_t)c * 512 + n] = (_Float16)0.0f;
    return;
  }
  __shared__ float Tc[512], Ts[512];
  __shared__ float wr[132], wi[132];
  for (int i = t; i < 512; i += 256) {
    float ang = (float)i * 0.0122718463030851f;  // 2*pi/512
    Tc[i] = cosf(ang);
    Ts[i] = sinf(ang);
  }
  int sub = (c >= 771) ? 3 : (c >= 514) ? 2 : (c >= 257) ? 1 : 0;
  int e = c - sub * 257;
  int Kn = (sub < 2) ? 128 : 129;
  int kb = (sub < 2) ? 0 : 128;
  if (t < Kn) {
    if (sub < 2) { wr[t] = l1r[t * 257 + e]; wi[t] = l1i[t * 257 + e]; }
    else         { wr[t] = h1r[t * 257 + e]; wi[t] = h1i[t * 257 + e]; }
  }
  __syncthreads();
  bool imag_out = (sub & 1);
  for (int n = t; n < 512; n += 256) {
    float acc = 0.f;
    for (int k = 0; k < Kn; ++k) {
      int kk = kb + k;
      int m = (n * kk) & 511;
      float Fr = Tc[m] * SC512;
      float Fi = -Ts[m] * SC512;
      if (!imag_out) acc += Fr * wr[k] - Fi * wi[k];
      else           acc += Fr * wi[k] + Fi * wr[k];
    }
    Wt[(size_t)c * 512 + n] = (_Float16)acc;
  }
}

// ---------------- build irfft matrix, B-transposed, matching OXh layout ----------------
// iDt[n][k], n in [0,512), k in [0,544). k<264: e=k cos part; 264..527: e=k-264 sin part.

__global__ __launch_bounds__(256) void build_idt(_Float16* __restrict__ iDt) {
  int idx = blockIdx.x * 256 + threadIdx.x;
  const int total = 512 * 544;
  if (idx >= total) return;
  int n = idx / 544;
  int k = idx - n * 544;
  float val = 0.f;
  if (k < 264) {
    int e = k;
    if (e <= 256) {
      float ce = (e == 0 || e == 256) ? 1.f : 2.f;
      int m = (n * e) & 511;
      val = ce * SC512 * cosf((float)m * 0.0122718463030851f);
    }
  } else if (k < 528) {
    int e = k - 264;
    if (e <= 256) {
      float ce = (e == 0 || e == 256) ? 1.f : 2.f;
      int m = (n * e) & 511;
      val = -ce * SC512 * sinf((float)m * 0.0122718463030851f);
    }
  }
  iDt[(size_t)n * 544 + k] = (_Float16)val;
}

// ---------------- MFMA f16 GEMM: LHf = relu(x @ W + bias) * S_FOLD ----------------
// M=32768, N=1028 (17 tiles of 64), K=512. A fp32 converted in staging, B = Wt f16 [c][k].
// grid (17, 256), block 256 (4 waves); tile 128(M) x 64(N), BK=32.

__global__ __launch_bounds__(256) void gemm_main(
    const float* __restrict__ X, const _Float16* __restrict__ Wt,
    const float* __restrict__ lbr, const float* __restrict__ lbi,
    const float* __restrict__ hbr, const float* __restrict__ hbi,
    _Float16* __restrict__ LHf) {
  __shared__ __align__(16) char lds[33792];
  _Float16* As = (_Float16*)lds;              // [128][40]
  _Float16* Bs = (_Float16*)(lds + 10240);    // [64][40]
  float* CL = (float*)lds;                    // [128][66]

  int t = threadIdx.x;
  int w = t >> 6, L = t & 63, q = L >> 4, lc = L & 15;
  int row0 = blockIdx.y * 128;
  int n0 = blockIdx.x * 64;

  f32x4 acc[2][4];
#pragma unroll
  for (int i = 0; i < 2; ++i)
#pragma unroll
    for (int j = 0; j < 4; ++j) acc[i][j] = f32x4{0.f, 0.f, 0.f, 0.f};

  for (int k0 = 0; k0 < 512; k0 += 32) {
    // stage A (fp32 -> f16)
    {
      int m = t >> 1, half = t & 1;
      const float* src = X + (size_t)(row0 + m) * 512 + k0 + half * 16;
      float4 a0 = *(const float4*)(src + 0);
      float4 a1 = *(const float4*)(src + 4);
      float4 a2 = *(const float4*)(src + 8);
      float4 a3 = *(const float4*)(src + 12);
      f16x8 h0 = {(_Float16)a0.x, (_Float16)a0.y, (_Float16)a0.z, (_Float16)a0.w,
                  (_Float16)a1.x, (_Float16)a1.y, (_Float16)a1.z, (_Float16)a1.w};
      f16x8 h1 = {(_Float16)a2.x, (_Float16)a2.y, (_Float16)a2.z, (_Float16)a2.w,
                  (_Float16)a3.x, (_Float16)a3.y, (_Float16)a3.z, (_Float16)a3.w};
      *(f16x8*)(As + m * 40 + half * 16) = h0;
      *(f16x8*)(As + m * 40 + half * 16 + 8) = h1;
    }
    // stage B
    {
      int row = t >> 2, ch = t & 3;
      f16x8 bv = *(const f16x8*)(Wt + (size_t)(n0 + row) * 512 + k0 + ch * 8);
      *(f16x8*)(Bs + row * 40 + ch * 8) = bv;
    }
    __syncthreads();
#pragma unroll
    for (int sub = 0; sub < 2; ++sub) {
      f16x8 af = *(const f16x8*)(As + (w * 32 + sub * 16 + lc) * 40 + q * 8);
#pragma unroll
      for (int ns = 0; ns < 4; ++ns) {
        f16x8 bf = *(const f16x8*)(Bs + (ns * 16 + lc) * 40 + q * 8);
        acc[sub][ns] = __builtin_amdgcn_mfma_f32_16x16x32_f16(af, bf, acc[sub][ns], 0, 0, 0);
      }
    }
    __syncthreads();
  }

  // epilogue: reorder via LDS, then bias+relu+scale+f16 pack into LHf
#pragma unroll
  for (int sub = 0; sub < 2; ++sub)
#pragma unroll
    for (int ns = 0; ns < 4; ++ns)
#pragma unroll
      for (int r = 0; r < 4; ++r)
        CL[(w * 32 + sub * 16 + q * 4 + r) * 66 + ns * 16 + lc] = acc[sub][ns][r];
  __syncthreads();

#pragma unroll
  for (int rep = 0; rep < 8; ++rep) {
    int idx = rep * 256 + t;
    int row = idx >> 4;
    int c4 = idx & 15;
    f32x4 v = *(const f32x4*)(CL + row * 66 + c4 * 4);
    int rowg = row0 + row;
#pragma unroll
    for (int jj = 0; jj < 4; ++jj) {
      int c = n0 + c4 * 4 + jj;
      if (c < 1028) {
        int sub = (c >= 771) ? 3 : (c >= 514) ? 2 : (c >= 257) ? 1 : 0;
        int e = c - sub * 257;
        float bv = (sub == 0) ? lbr[e] : (sub == 1) ? lbi[e] : (sub == 2) ? hbr[e] : hbi[e];
        float val = fmaxf(v[jj] + bv, 0.f) * S_FOLD;
        LHf[(size_t)rowg * LD16 + sub * 264 + e] = (_Float16)val;
      }
    }
  }
}

// ---------------- repack K into MFMA B-frag-linear order ----------------
// Kpack chunk wc = (((b*2+pass)*2+comp)*32 + jt)*9 + ec ; chunk = [64 lanes][8 halves].
// Lane L: j = jt*16 + (L&15), e = ec*32 + (L>>4)*8 + i.

__global__ __launch_bounds__(256) void repack_K(
    const _Float16* __restrict__ LHf, _Float16* __restrict__ Kpack) {
  int t = threadIdx.x;
  int w = t >> 6, L = t & 63, q = L >> 4, lc = L & 15;
  int wc = blockIdx.x * 4 + w;
  int ec = wc % 9;
  int tmp = wc / 9;
  int jt = tmp & 31; tmp >>= 5;
  int comp = tmp & 1; tmp >>= 1;
  int pass = tmp & 1;
  int b = tmp >> 1;
  f16x8 v;
  if (ec == 8 && q > 0) {
    v = f16x8{(_Float16)0, (_Float16)0, (_Float16)0, (_Float16)0,
              (_Float16)0, (_Float16)0, (_Float16)0, (_Float16)0};
  } else {
    v = *(const f16x8*)(LHf + (size_t)(b * 512 + jt * 16 + lc) * LD16 +
                        pass * 528 + comp * 264 + ec * 32 + q * 8);
  }
  *(f16x8*)(Kpack + (size_t)wc * 512 + L * 8) = v;
}

// ---------------- repack V (low) into PV B-frag order via LDS transpose ----------------
// Vpack[b][comp][et(17)][ks(16)][64 lanes][8]; lane L: e = et*16+(L&15), j = ks*32+(L>>4)*8+i.

__global__ __launch_bounds__(256) void repack_V(
    const _Float16* __restrict__ LHf, _Float16* __restrict__ Vpack) {
  int bid = blockIdx.x;
  int et = bid % 17;
  int tmp = bid / 17;
  int comp = tmp & 1;
  int b = tmp >> 1;
  int t = threadIdx.x;
  __shared__ __align__(16) _Float16 tile[512 * 16];

  const f16x8 zero8 = {(_Float16)0, (_Float16)0, (_Float16)0, (_Float16)0,
                       (_Float16)0, (_Float16)0, (_Float16)0, (_Float16)0};
  for (int j = t; j < 512; j += 256) {
    const _Float16* src = LHf + (size_t)(b * 512 + j) * LD16 + comp * 264 + et * 16;
    f16x8 v0, v1;
    if (et < 16) {
      v0 = *(const f16x8*)(src);
      v1 = *(const f16x8*)(src + 8);
    } else {  // e = 256..271: only first 8 within sub-block (256 real, 257..263 zero)
      v0 = *(const f16x8*)(src);
      v1 = zero8;
    }
    *(f16x8*)(tile + j * 16) = v0;
    *(f16x8*)(tile + j * 16 + 8) = v1;
  }
  __syncthreads();

#pragma unroll
  for (int it = 0; it < 4; ++it) {
    int c2 = it * 256 + t;
    int ks = c2 >> 6;
    int L2 = c2 & 63;
    int q2 = L2 >> 4, lc2 = L2 & 15;
    f16x8 v;
#pragma unroll
    for (int i = 0; i < 8; ++i) v[i] = tile[(ks * 32 + q2 * 8 + i) * 16 + lc2];
    *(f16x8*)(Vpack + ((((size_t)(b * 2 + comp) * 17 + et) * 16 + ks) * 512) + L2 * 8) = v;
  }
}

// ---------------- DPP 16-lane reductions (VALU pipe, no DS latency) ----------------

template <int CTRL>
__device__ __forceinline__ float dpp_f32(float x) {
  return __int_as_float(
      __builtin_amdgcn_update_dpp(0, __float_as_int(x), CTRL, 0xF, 0xF, true));
}

__device__ __forceinline__ float red_max16(float x) {
  x = fmaxf(x, dpp_f32<0xB1>(x));
  x = fmaxf(x, dpp_f32<0x4E>(x));
  x = fmaxf(x, dpp_f32<0x141>(x));
  x = fmaxf(x, dpp_f32<0x140>(x));
  return x;
}

__device__ __forceinline__ float red_sum16(float x) {
  x += dpp_f32<0xB1>(x);
  x += dpp_f32<0x4E>(x);
  x += dpp_f32<0x141>(x);
  x += dpp_f32<0x140>(x);
  return x;
}

// ---------------- MFMA f16 flash attention, DEFERRED PV, 3 blocks/CU ----------------
// Q fragments in registers (72 VGPR, affordable after deferred-PV shrank acc to 40).
// P stored in sP2[comp][ks][qw][row][i]: the PV A-frag read is base + L*16B, i.e.
// lane-contiguous across the wave -> zero LDS bank conflicts (round-3 layout was 8-way).
// LDS total 40KB; __launch_bounds__(256,3) caps VGPR at 170 -> 3 blocks/CU (round-3: 2).
// Per pass: phase1 (QK + DPP local softmax, no barriers) -> barrier -> stat merge ->
// PV with pre-normalized A-frags (no barriers) -> barrier.

__global__ __launch_bounds__(256, 3) void attn_mfma3(
    const _Float16* __restrict__ LHf, const _Float16* __restrict__ Kpack,
    const _Float16* __restrict__ Vpack, _Float16* __restrict__ OXh) {
  int bid = blockIdx.x;
  int xcd = bid & 7;
  int ix = bid >> 3;
  int rt = ix & 31;
  int b = xcd + 8 * (ix >> 5);
  int t = threadIdx.x;
  int w = t >> 6, L = t & 63, q = L >> 4, lc = L & 15;

  __shared__ __align__(16) _Float16 sP2[2][16][4][16][8];  // 32 KB, conflict-free reads
  __shared__ __align__(16) float sMall[2][16][32];         // 4 KB: local max per 16-j tile
  __shared__ __align__(16) float sSall[2][16][32];         // 4 KB: local sum per 16-j tile

  const f16x8 zero8 = {(_Float16)0, (_Float16)0, (_Float16)0, (_Float16)0,
                       (_Float16)0, (_Float16)0, (_Float16)0, (_Float16)0};

  // resident Q fragments (A-frag: m=lc, k=ec*32+q*8+i), gathered once from L2
  const _Float16* qbase = LHf + (size_t)(b * 512 + rt * 16 + lc) * LD16;
  f16x8 Qf[2][9];
#pragma unroll
  for (int comp = 0; comp < 2; ++comp)
#pragma unroll
    for (int ec = 0; ec < 9; ++ec)
      Qf[comp][ec] = (ec == 8 && q != 0)
                         ? zero8
                         : *(const f16x8*)(qbase + comp * 264 + ec * 32 + q * 8);

  int t0 = (w == 0) ? 0 : (4 * w + 1);   // et tiles {0..4},{5..8},{9..12},{13..16}
  int nt = (w == 0) ? 5 : 4;
  int h = q >> 1;

  f32x4 accR[5], accI[5];  // final normalized outputs, accumulated across passes
#pragma unroll
  for (int i = 0; i < 5; ++i) {
    accR[i] = f32x4{0.f, 0.f, 0.f, 0.f};
    accI[i] = f32x4{0.f, 0.f, 0.f, 0.f};
  }

  // P-write decomposition of this lane's j column: j = (jt*4+w)*16 + lc
  for (int pass = 0; pass < 2; ++pass) {
    // ================= phase 1: QK + local softmax, no barriers =================
    for (int jt = 0; jt < 8; ++jt) {
      size_t kb0 = ((((size_t)(b * 2 + pass) * 2 + 0) * 32 + (jt * 4 + w)) * 9) * 512;
      size_t kb1 = ((((size_t)(b * 2 + pass) * 2 + 1) * 32 + (jt * 4 + w)) * 9) * 512;
      f32x4 sRR = f32x4{0.f, 0.f, 0.f, 0.f};
      f32x4 sII = f32x4{0.f, 0.f, 0.f, 0.f};
      f32x4 sRI = f32x4{0.f, 0.f, 0.f, 0.f};
      f32x4 sIR = f32x4{0.f, 0.f, 0.f, 0.f};
      __builtin_amdgcn_s_setprio(1);
#pragma unroll
      for (int ec = 0; ec < 9; ++ec) {
        f16x8 bKr = *(const f16x8*)(Kpack + kb0 + (size_t)ec * 512 + L * 8);
        f16x8 bKi = *(const f16x8*)(Kpack + kb1 + (size_t)ec * 512 + L * 8);
        sRR = __builtin_amdgcn_mfma_f32_16x16x32_f16(Qf[0][ec], bKr, sRR, 0, 0, 0);
        sII = __builtin_amdgcn_mfma_f32_16x16x32_f16(Qf[1][ec], bKi, sII, 0, 0, 0);
        sRI = __builtin_amdgcn_mfma_f32_16x16x32_f16(Qf[0][ec], bKi, sRI, 0, 0, 0);
        sIR = __builtin_amdgcn_mfma_f32_16x16x32_f16(Qf[1][ec], bKr, sIR, 0, 0, 0);
      }
      __builtin_amdgcn_s_setprio(0);

      int jj = (jt * 4 + w) * 16 + lc;
      int ksw = jj >> 5, qw = (jj >> 3) & 3, iw = jj & 7;
      int jtile = jt * 4 + w;
#pragma unroll
      for (int r = 0; r < 4; ++r) {
        float vr = sRR[r] - sII[r];
        float vi = sRI[r] + sIR[r];
        float mlr = red_max16(vr);
        float mli = red_max16(vi);
        float ur = __expf(vr - mlr);
        float ui = __expf(vi - mli);
        int row = q * 4 + r;
        sP2[0][ksw][qw][row][iw] = (_Float16)ur;
        sP2[1][ksw][qw][row][iw] = (_Float16)ui;
        float sr = red_sum16(ur);
        float si = red_sum16(ui);
        if (lc == 0) {
          sMall[0][row][jtile] = mlr;
          sSall[0][row][jtile] = sr;
          sMall[1][row][jtile] = mli;
          sSall[1][row][jtile] = si;
        }
      }
    }
    __syncthreads();  // P + stats published

    // ================= stat merge for row lc =================
    float mfR = -3.0e38f, mfI = -3.0e38f;
#pragma unroll
    for (int j4 = 0; j4 < 8; ++j4) {
      f32x4 a = *(const f32x4*)&sMall[0][lc][j4 * 4];
      f32x4 c = *(const f32x4*)&sMall[1][lc][j4 * 4];
      mfR = fmaxf(mfR, fmaxf(fmaxf(a[0], a[1]), fmaxf(a[2], a[3])));
      mfI = fmaxf(mfI, fmaxf(fmaxf(c[0], c[1]), fmaxf(c[2], c[3])));
    }
    float lR = 0.f, lI = 0.f;
#pragma unroll
    for (int j4 = 0; j4 < 8; ++j4) {
      f32x4 mr = *(const f32x4*)&sMall[0][lc][j4 * 4];
      f32x4 sr = *(const f32x4*)&sSall[0][lc][j4 * 4];
      f32x4 mi = *(const f32x4*)&sMall[1][lc][j4 * 4];
      f32x4 si = *(const f32x4*)&sSall[1][lc][j4 * 4];
#pragma unroll
      for (int kk = 0; kk < 4; ++kk) {
        lR += sr[kk] * __expf(mr[kk] - mfR);
        lI += si[kk] * __expf(mi[kk] - mfI);
      }
    }
    float gRb = INV_S / lR;
    float gIb = INV_S / lI;

    // ================= PV: pre-normalized A-frags, 2 accs, no barriers =========
    for (int ks = 0; ks < 16; ++ks) {
      int jtA = ks * 2 + h;
      float gR = __expf(sMall[0][lc][jtA] - mfR) * gRb;
      float gI = __expf(sMall[1][lc][jtA] - mfI) * gIb;
      f16x8 uR = *(const f16x8*)&sP2[0][ks][q][lc][0];
      f16x8 uI = *(const f16x8*)&sP2[1][ks][q][lc][0];
      _Float16 hR = (_Float16)gR;
      _Float16 hI = (_Float16)gI;
      _Float16 hmI = (_Float16)(-gI);
      f16x8 aR, aI, amI;
#pragma unroll
      for (int i = 0; i < 8; ++i) {
        aR[i] = uR[i] * hR;
        aI[i] = uI[i] * hI;
        amI[i] = uI[i] * hmI;
      }
      __builtin_amdgcn_s_setprio(1);
#pragma unroll
      for (int ti = 0; ti < 5; ++ti) {
        if (ti < nt) {
          int et = t0 + ti;
          size_t vb = (((size_t)(b * 2 + 0) * 17 + et) * 16 + ks) * 512;
          size_t vb2 = (((size_t)(b * 2 + 1) * 17 + et) * 16 + ks) * 512;
          f16x8 bVr = *(const f16x8*)(Vpack + vb + L * 8);
          f16x8 bVi = *(const f16x8*)(Vpack + vb2 + L * 8);
          accR[ti] = __builtin_amdgcn_mfma_f32_16x16x32_f16(aR, bVr, accR[ti], 0, 0, 0);
          accR[ti] = __builtin_amdgcn_mfma_f32_16x16x32_f16(amI, bVi, accR[ti], 0, 0, 0);
          accI[ti] = __builtin_amdgcn_mfma_f32_16x16x32_f16(aR, bVi, accI[ti], 0, 0, 0);
          accI[ti] = __builtin_amdgcn_mfma_f32_16x16x32_f16(aI, bVr, accI[ti], 0, 0, 0);
        }
      }
      __builtin_amdgcn_s_setprio(0);
    }
    __syncthreads();  // sP2/sMall/sSall reused by next pass's phase 1
  }

  // ---- store OXh f16 rows into LHf[.][528..1056) ----
  _Float16* obase = OXh + (size_t)(b * 512 + rt * 16) * LD16 + OXOFF;
#pragma unroll
  for (int ti = 0; ti < 5; ++ti) {
    if (ti < nt) {
      int e = (t0 + ti) * 16 + lc;
      if (e < 257) {
#pragma unroll
        for (int r = 0; r < 4; ++r) {
          _Float16* dst = obase + (size_t)(q * 4 + r) * LD16;
          dst[e] = (_Float16)accR[ti][r];
          dst[264 + e] = (_Float16)accI[ti][r];
        }
      }
    }
  }
}

// ---------------- MFMA f16 GEMM: out = OXh @ iDt ----------------
// M=32768, N=512 (8 tiles), K=528 (pad 544). A = LHf+OXOFF (f16, ld 1056).

__global__ __launch_bounds__(256) void gemm_irfft(
    const _Float16* __restrict__ LHf, const _Float16* __restrict__ iDt,
    float* __restrict__ out) {
  __shared__ __align__(16) char lds[33792];
  _Float16* As = (_Float16*)lds;              // [128][40]
  _Float16* Bs = (_Float16*)(lds + 10240);    // [64][40]
  float* CL = (float*)lds;                    // [128][66]

  int t = threadIdx.x;
  int w = t >> 6, L = t & 63, q = L >> 4, lc = L & 15;
  int row0 = blockIdx.y * 128;
  int n0 = blockIdx.x * 64;

  const f16x8 zero8 = {(_Float16)0, (_Float16)0, (_Float16)0, (_Float16)0,
                       (_Float16)0, (_Float16)0, (_Float16)0, (_Float16)0};

  f32x4 acc[2][4];
#pragma unroll
  for (int i = 0; i < 2; ++i)
#pragma unroll
    for (int j = 0; j < 4; ++j) acc[i][j] = f32x4{0.f, 0.f, 0.f, 0.f};

  for (int k0 = 0; k0 < 544; k0 += 32) {
    {
      int m = t >> 1, half = t & 1;
      int kk = k0 + half * 16;
      f16x8 h0, h1;
      if (kk < 528) {
        const _Float16* src = LHf + (size_t)(row0 + m) * LD16 + OXOFF + kk;
        h0 = *(const f16x8*)(src);
        h1 = *(const f16x8*)(src + 8);
      } else {
        h0 = zero8; h1 = zero8;
      }
      *(f16x8*)(As + m * 40 + half * 16) = h0;
      *(f16x8*)(As + m * 40 + half * 16 + 8) = h1;
    }
    {
      int row = t >> 2, ch = t & 3;
      f16x8 bv = *(const f16x8*)(iDt + (size_t)(n0 + row) * 544 + k0 + ch * 8);
      *(f16x8*)(Bs + row * 40 + ch * 8) = bv;
    }
    __syncthreads();
#pragma unroll
    for (int sub = 0; sub < 2; ++sub) {
      f16x8 af = *(const f16x8*)(As + (w * 32 + sub * 16 + lc) * 40 + q * 8);
#pragma unroll
      for (int ns = 0; ns < 4; ++ns) {
        f16x8 bf = *(const f16x8*)(Bs + (ns * 16 + lc) * 40 + q * 8);
        acc[sub][ns] = __builtin_amdgcn_mfma_f32_16x16x32_f16(af, bf, acc[sub][ns], 0, 0, 0);
      }
    }
    __syncthreads();
  }

#pragma unroll
  for (int sub = 0; sub < 2; ++sub)
#pragma unroll
    for (int ns = 0; ns < 4; ++ns)
#pragma unroll
      for (int r = 0; r < 4; ++r)
        CL[(w * 32 + sub * 16 + q * 4 + r) * 66 + ns * 16 + lc] = acc[sub][ns][r];
  __syncthreads();

#pragma unroll
  for (int rep = 0; rep < 8; ++rep) {
    int idx = rep * 256 + t;
    int row = idx >> 4;
    int c4 = idx & 15;
    f32x4 v = *(const f32x4*)(CL + row * 66 + c4 * 4);
    float4 o = {v[0], v[1], v[2], v[3]};
    *(float4*)(out + (size_t)(row0 + row) * 512 + n0 + c4 * 4) = o;
  }
}

// ---------------- launch ----------------

extern "C" void kernel_launch(void* const* d_in, const int* in_sizes, int n_in,
                              void* d_out, int out_size, void* d_ws, size_t ws_size,
                              hipStream_t stream) {
  const float* x   = (const float*)d_in[0];
  const float* l1r = (const float*)d_in[1];
  const float* l1i = (const float*)d_in[2];
  const float* h1r = (const float*)d_in[3];
  const float* h1i = (const float*)d_in[4];
  const float* lbr = (const float*)d_in[5];
  const float* lbi = (const float*)d_in[6];
  const float* hbr = (const float*)d_in[7];
  const float* hbi = (const float*)d_in[8];
  float* out = (float*)d_out;

  _Float16* ws = (_Float16*)d_ws;
  size_t off = 0;
  _Float16* LHf = ws + off;   off += (size_t)32768 * LD16;        // 69.2 MB
  _Float16* Kpack = ws + off; off += (size_t)73728 * 512;         // 75.5 MB
  _Float16* Vpack = ws + off; off += (size_t)64 * 2 * 17 * 16 * 512;  // 35.7 MB
  _Float16* Wt = ws + off;    off += (size_t)1088 * 512;          // 1.1 MB
  _Float16* iDt = ws + off;   off += (size_t)512 * 544;           // 0.6 MB

  hipMemsetAsync(LHf, 0, (size_t)32768 * LD16 * 2, stream);

  build_W<<<1088, 256, 0, stream>>>(l1r, l1i, h1r, h1i, Wt);
  build_idt<<<(512 * 544 + 255) / 256, 256, 0, stream>>>(iDt);

  gemm_main<<<dim3(17, 256), 256, 0, stream>>>(x, Wt, lbr, lbi, hbr, hbi, LHf);
  repack_K<<<73728 / 4, 256, 0, stream>>>(LHf, Kpack);
  repack_V<<<64 * 2 * 17, 256, 0, stream>>>(LHf, Vpack);
  attn_mfma3<<<2048, 256, 0, stream>>>(LHf, Kpack, Vpack, LHf);
  gemm_irfft<<<dim3(8, 256), 256, 0, stream>>>(LHf, iDt, out);
}

// Round 6
// 733.955 us; speedup vs baseline: 1.2893x; 1.2893x over previous
//
#include <hip/hip_runtime.h>
#include <math.h>

// B=64, C=512, S=512, E=257, LK=128, HK=129.
// high_x is dead code in the reference: only low_x = attn(low,low,low)+attn(low,high,low).
//
// Pipeline (all heavy math on MFMA f16):
//  1. build_W: Wt[c][n] f16 = combined rfft+projection weight (512 -> 1028), B-transposed
//  2. build_idt: iDt[n][k] f16 = irfft matrix matching OXh row layout [re264|im264]
//  3. gemm_main (MFMA f16): LHf = relu(x @ W + bias) * S_FOLD, f16 rows [lr|li|hr|hi] (264 pad)
//  4. repack_K: LHf -> Kpack in exact MFMA B-frag order (coalesced attention loads)
//  5. repack_V: LHf low -> Vpack (LDS transpose) in PV B-frag order
//  6. attn (MFMA f16 flash, DEFERRED PV): Q in chunk-linear LDS (conflict-free), P in
//     lane-linear LDS, f16 stats with conflict-free stride-18 layout, 3 blocks/CU
//     (LDS 53.76KB, VGPR ~100 under the 170 cap -> no spill; round-4 spilled Qf).
//  7. gemm_irfft (MFMA f16): out = OXh @ iDt
//
// ws: LHf 69.2 MB + Kpack 75.5 MB + Vpack 35.7 MB + Wt 1.1 MB + iDt 0.6 MB ~= 182 MB.

#define LD16 1056   // halves per LHf row: [lr 264 | li 264 | hr 264 | hi 264]
#define OXOFF 528   // OXh f16 output written into LHf[row][528..1056): [re 264 | im 264]

typedef __attribute__((ext_vector_type(4))) _Float16 f16x4;
typedef __attribute__((ext_vector_type(8))) _Float16 f16x8;
typedef __attribute__((ext_vector_type(4))) float f32x4;

#define S_FOLD 0.24975653f    // sqrt(1/sqrt(257))
#define INV_S  4.0039005f     // 1/S_FOLD
#define SC512  0.0441941738241592f   // 1/sqrt(512)

// ---------------- build combined rfft+projection weight, B-transposed ----------------

__global__ __launch_bounds__(256) void build_W(
    const float* __restrict__ l1r, const float* __restrict__ l1i,
    const float* __restrict__ h1r, const float* __restrict__ h1i,
    _Float16* __restrict__ Wt) {
  int c = blockIdx.x;
  int t = threadIdx.x;
  if (c >= 1028) {
    for (int n = t; n < 512; n += 256) Wt[(size_t)c * 512 + n] = (_Float16)0.0f;
    return;
  }
  __shared__ float Tc[512], Ts[512];
  __shared__ float wr[132], wi[132];
  for (int i = t; i < 512; i += 256) {
    float ang = (float)i * 0.0122718463030851f;  // 2*pi/512
    Tc[i] = cosf(ang);
    Ts[i] = sinf(ang);
  }
  int sub = (c >= 771) ? 3 : (c >= 514) ? 2 : (c >= 257) ? 1 : 0;
  int e = c - sub * 257;
  int Kn = (sub < 2) ? 128 : 129;
  int kb = (sub < 2) ? 0 : 128;
  if (t < Kn) {
    if (sub < 2) { wr[t] = l1r[t * 257 + e]; wi[t] = l1i[t * 257 + e]; }
    else         { wr[t] = h1r[t * 257 + e]; wi[t] = h1i[t * 257 + e]; }
  }
  __syncthreads();
  bool imag_out = (sub & 1);
  for (int n = t; n < 512; n += 256) {
    float acc = 0.f;
    for (int k = 0; k < Kn; ++k) {
      int kk = kb + k;
      int m = (n * kk) & 511;
      float Fr = Tc[m] * SC512;
      float Fi = -Ts[m] * SC512;
      if (!imag_out) acc += Fr * wr[k] - Fi * wi[k];
      else           acc += Fr * wi[k] + Fi * wr[k];
    }
    Wt[(size_t)c * 512 + n] = (_Float16)acc;
  }
}

// ---------------- build irfft matrix, B-transposed, matching OXh layout ----------------

__global__ __launch_bounds__(256) void build_idt(_Float16* __restrict__ iDt) {
  int idx = blockIdx.x * 256 + threadIdx.x;
  const int total = 512 * 544;
  if (idx >= total) return;
  int n = idx / 544;
  int k = idx - n * 544;
  float val = 0.f;
  if (k < 264) {
    int e = k;
    if (e <= 256) {
      float ce = (e == 0 || e == 256) ? 1.f : 2.f;
      int m = (n * e) & 511;
      val = ce * SC512 * cosf((float)m * 0.0122718463030851f);
    }
  } else if (k < 528) {
    int e = k - 264;
    if (e <= 256) {
      float ce = (e == 0 || e == 256) ? 1.f : 2.f;
      int m = (n * e) & 511;
      val = -ce * SC512 * sinf((float)m * 0.0122718463030851f);
    }
  }
  iDt[(size_t)n * 544 + k] = (_Float16)val;
}

// ---------------- MFMA f16 GEMM: LHf = relu(x @ W + bias) * S_FOLD ----------------

__global__ __launch_bounds__(256) void gemm_main(
    const float* __restrict__ X, const _Float16* __restrict__ Wt,
    const float* __restrict__ lbr, const float* __restrict__ lbi,
    const float* __restrict__ hbr, const float* __restrict__ hbi,
    _Float16* __restrict__ LHf) {
  __shared__ __align__(16) char lds[33792];
  _Float16* As = (_Float16*)lds;              // [128][40]
  _Float16* Bs = (_Float16*)(lds + 10240);    // [64][40]
  float* CL = (float*)lds;                    // [128][66]

  int t = threadIdx.x;
  int w = t >> 6, L = t & 63, q = L >> 4, lc = L & 15;
  int row0 = blockIdx.y * 128;
  int n0 = blockIdx.x * 64;

  f32x4 acc[2][4];
#pragma unroll
  for (int i = 0; i < 2; ++i)
#pragma unroll
    for (int j = 0; j < 4; ++j) acc[i][j] = f32x4{0.f, 0.f, 0.f, 0.f};

  for (int k0 = 0; k0 < 512; k0 += 32) {
    {
      int m = t >> 1, half = t & 1;
      const float* src = X + (size_t)(row0 + m) * 512 + k0 + half * 16;
      float4 a0 = *(const float4*)(src + 0);
      float4 a1 = *(const float4*)(src + 4);
      float4 a2 = *(const float4*)(src + 8);
      float4 a3 = *(const float4*)(src + 12);
      f16x8 h0 = {(_Float16)a0.x, (_Float16)a0.y, (_Float16)a0.z, (_Float16)a0.w,
                  (_Float16)a1.x, (_Float16)a1.y, (_Float16)a1.z, (_Float16)a1.w};
      f16x8 h1 = {(_Float16)a2.x, (_Float16)a2.y, (_Float16)a2.z, (_Float16)a2.w,
                  (_Float16)a3.x, (_Float16)a3.y, (_Float16)a3.z, (_Float16)a3.w};
      *(f16x8*)(As + m * 40 + half * 16) = h0;
      *(f16x8*)(As + m * 40 + half * 16 + 8) = h1;
    }
    {
      int row = t >> 2, ch = t & 3;
      f16x8 bv = *(const f16x8*)(Wt + (size_t)(n0 + row) * 512 + k0 + ch * 8);
      *(f16x8*)(Bs + row * 40 + ch * 8) = bv;
    }
    __syncthreads();
#pragma unroll
    for (int sub = 0; sub < 2; ++sub) {
      f16x8 af = *(const f16x8*)(As + (w * 32 + sub * 16 + lc) * 40 + q * 8);
#pragma unroll
      for (int ns = 0; ns < 4; ++ns) {
        f16x8 bf = *(const f16x8*)(Bs + (ns * 16 + lc) * 40 + q * 8);
        acc[sub][ns] = __builtin_amdgcn_mfma_f32_16x16x32_f16(af, bf, acc[sub][ns], 0, 0, 0);
      }
    }
    __syncthreads();
  }

#pragma unroll
  for (int sub = 0; sub < 2; ++sub)
#pragma unroll
    for (int ns = 0; ns < 4; ++ns)
#pragma unroll
      for (int r = 0; r < 4; ++r)
        CL[(w * 32 + sub * 16 + q * 4 + r) * 66 + ns * 16 + lc] = acc[sub][ns][r];
  __syncthreads();

#pragma unroll
  for (int rep = 0; rep < 8; ++rep) {
    int idx = rep * 256 + t;
    int row = idx >> 4;
    int c4 = idx & 15;
    f32x4 v = *(const f32x4*)(CL + row * 66 + c4 * 4);
    int rowg = row0 + row;
#pragma unroll
    for (int jj = 0; jj < 4; ++jj) {
      int c = n0 + c4 * 4 + jj;
      if (c < 1028) {
        int sub = (c >= 771) ? 3 : (c >= 514) ? 2 : (c >= 257) ? 1 : 0;
        int e = c - sub * 257;
        float bv = (sub == 0) ? lbr[e] : (sub == 1) ? lbi[e] : (sub == 2) ? hbr[e] : hbi[e];
        float val = fmaxf(v[jj] + bv, 0.f) * S_FOLD;
        LHf[(size_t)rowg * LD16 + sub * 264 + e] = (_Float16)val;
      }
    }
  }
}

// ---------------- repack K into MFMA B-frag-linear order ----------------

__global__ __launch_bounds__(256) void repack_K(
    const _Float16* __restrict__ LHf, _Float16* __restrict__ Kpack) {
  int t = threadIdx.x;
  int w = t >> 6, L = t & 63, q = L >> 4, lc = L & 15;
  int wc = blockIdx.x * 4 + w;
  int ec = wc % 9;
  int tmp = wc / 9;
  int jt = tmp & 31; tmp >>= 5;
  int comp = tmp & 1; tmp >>= 1;
  int pass = tmp & 1;
  int b = tmp >> 1;
  f16x8 v;
  if (ec == 8 && q > 0) {
    v = f16x8{(_Float16)0, (_Float16)0, (_Float16)0, (_Float16)0,
              (_Float16)0, (_Float16)0, (_Float16)0, (_Float16)0};
  } else {
    v = *(const f16x8*)(LHf + (size_t)(b * 512 + jt * 16 + lc) * LD16 +
                        pass * 528 + comp * 264 + ec * 32 + q * 8);
  }
  *(f16x8*)(Kpack + (size_t)wc * 512 + L * 8) = v;
}

// ---------------- repack V (low) into PV B-frag order via LDS transpose ----------------

__global__ __launch_bounds__(256) void repack_V(
    const _Float16* __restrict__ LHf, _Float16* __restrict__ Vpack) {
  int bid = blockIdx.x;
  int et = bid % 17;
  int tmp = bid / 17;
  int comp = tmp & 1;
  int b = tmp >> 1;
  int t = threadIdx.x;
  __shared__ __align__(16) _Float16 tile[512 * 16];

  const f16x8 zero8 = {(_Float16)0, (_Float16)0, (_Float16)0, (_Float16)0,
                       (_Float16)0, (_Float16)0, (_Float16)0, (_Float16)0};
  for (int j = t; j < 512; j += 256) {
    const _Float16* src = LHf + (size_t)(b * 512 + j) * LD16 + comp * 264 + et * 16;
    f16x8 v0, v1;
    if (et < 16) {
      v0 = *(const f16x8*)(src);
      v1 = *(const f16x8*)(src + 8);
    } else {
      v0 = *(const f16x8*)(src);
      v1 = zero8;
    }
    *(f16x8*)(tile + j * 16) = v0;
    *(f16x8*)(tile + j * 16 + 8) = v1;
  }
  __syncthreads();

#pragma unroll
  for (int it = 0; it < 4; ++it) {
    int c2 = it * 256 + t;
    int ks = c2 >> 6;
    int L2 = c2 & 63;
    int q2 = L2 >> 4, lc2 = L2 & 15;
    f16x8 v;
#pragma unroll
    for (int i = 0; i < 8; ++i) v[i] = tile[(ks * 32 + q2 * 8 + i) * 16 + lc2];
    *(f16x8*)(Vpack + ((((size_t)(b * 2 + comp) * 17 + et) * 16 + ks) * 512) + L2 * 8) = v;
  }
}

// ---------------- DPP 16-lane reductions (VALU pipe, no DS latency) ----------------

template <int CTRL>
__device__ __forceinline__ float dpp_f32(float x) {
  return __int_as_float(
      __builtin_amdgcn_update_dpp(0, __float_as_int(x), CTRL, 0xF, 0xF, true));
}

__device__ __forceinline__ float red_max16(float x) {
  x = fmaxf(x, dpp_f32<0xB1>(x));
  x = fmaxf(x, dpp_f32<0x4E>(x));
  x = fmaxf(x, dpp_f32<0x141>(x));
  x = fmaxf(x, dpp_f32<0x140>(x));
  return x;
}

__device__ __forceinline__ float red_sum16(float x) {
  x += dpp_f32<0xB1>(x);
  x += dpp_f32<0x4E>(x);
  x += dpp_f32<0x141>(x);
  x += dpp_f32<0x140>(x);
  return x;
}

// ---------------- MFMA f16 flash attention, DEFERRED PV, 3 blocks/CU ----------------
// LDS (53.76 KB total, all accesses bank-conflict-free):
//   sQc[comp][ec<8][64][8]  (16.4 KB): chunk-linear; fill and QK reads are base+L*16B.
//   Qf8[comp] in registers  (8 VGPR): ec==8 fragment (only q==0 lanes hold data).
//   sP2[comp][ks][qw][16][8] (32 KB): PV A-frag read is base+L*16B (lane-linear).
//   sM/sS f16 [comp][jtile32][18] (4.5 KB): stride 18 halves = 9 dwords -> reads
//     (j*9 + lc/2) and writes ((q*4+r) offsets) hit distinct banks.
// f16 stats are numerically consistent: u is computed against the f16-ROUNDED local
// max (u = exp(v - float(f16(m)))), so rounding introduces no weight inconsistency.
// VGPR ~100 under the launch_bounds(256,3) cap of 170 -> no spill (round-4 bug).

__global__ __launch_bounds__(256, 3) void attn_mfma3(
    const _Float16* __restrict__ LHf, const _Float16* __restrict__ Kpack,
    const _Float16* __restrict__ Vpack, _Float16* __restrict__ OXh) {
  int bid = blockIdx.x;
  int xcd = bid & 7;
  int ix = bid >> 3;
  int rt = ix & 31;
  int b = xcd + 8 * (ix >> 5);
  int t = threadIdx.x;
  int w = t >> 6, L = t & 63, q = L >> 4, lc = L & 15;

  __shared__ __align__(16) _Float16 sQc[2][8][64][8];      // 16384 B
  __shared__ __align__(16) _Float16 sP2[2][16][4][16][8];  // 32768 B
  __shared__ __align__(16) _Float16 sM[2][32][18];         // 2304 B
  __shared__ __align__(16) _Float16 sS[2][32][18];         // 2304 B

  const f16x8 zero8 = {(_Float16)0, (_Float16)0, (_Float16)0, (_Float16)0,
                       (_Float16)0, (_Float16)0, (_Float16)0, (_Float16)0};

  // fill sQc (chunk-linear: lane L owns slot [comp][ec][L]) + Qf8 in regs
  const _Float16* qbase = LHf + (size_t)(b * 512 + rt * 16 + lc) * LD16;
  f16x8 Qf8[2];
#pragma unroll
  for (int comp = 0; comp < 2; ++comp)
    Qf8[comp] = (q == 0) ? *(const f16x8*)(qbase + comp * 264 + 256) : zero8;
  for (int g = w; g < 16; g += 4) {
    int comp = g >> 3, ec = g & 7;
    f16x8 v = *(const f16x8*)(qbase + comp * 264 + ec * 32 + q * 8);
    *(f16x8*)(&sQc[comp][ec][L][0]) = v;
  }
  __syncthreads();

  int t0 = (w == 0) ? 0 : (4 * w + 1);   // et tiles {0..4},{5..8},{9..12},{13..16}
  int nt = (w == 0) ? 5 : 4;
  int h = q >> 1;

  f32x4 accR[5], accI[5];  // final normalized outputs, accumulated across passes
#pragma unroll
  for (int i = 0; i < 5; ++i) {
    accR[i] = f32x4{0.f, 0.f, 0.f, 0.f};
    accI[i] = f32x4{0.f, 0.f, 0.f, 0.f};
  }

  for (int pass = 0; pass < 2; ++pass) {
    // ================= phase 1: QK + local softmax, no barriers =================
    for (int jt = 0; jt < 8; ++jt) {
      size_t kb0 = ((((size_t)(b * 2 + pass) * 2 + 0) * 32 + (jt * 4 + w)) * 9) * 512;
      size_t kb1 = ((((size_t)(b * 2 + pass) * 2 + 1) * 32 + (jt * 4 + w)) * 9) * 512;
      f32x4 sRR = f32x4{0.f, 0.f, 0.f, 0.f};
      f32x4 sII = f32x4{0.f, 0.f, 0.f, 0.f};
      f32x4 sRI = f32x4{0.f, 0.f, 0.f, 0.f};
      f32x4 sIR = f32x4{0.f, 0.f, 0.f, 0.f};
      __builtin_amdgcn_s_setprio(1);
#pragma unroll
      for (int ec = 0; ec < 8; ++ec) {
        f16x8 bKr = *(const f16x8*)(Kpack + kb0 + (size_t)ec * 512 + L * 8);
        f16x8 bKi = *(const f16x8*)(Kpack + kb1 + (size_t)ec * 512 + L * 8);
        f16x8 q0 = *(const f16x8*)(&sQc[0][ec][L][0]);
        f16x8 q1 = *(const f16x8*)(&sQc[1][ec][L][0]);
        sRR = __builtin_amdgcn_mfma_f32_16x16x32_f16(q0, bKr, sRR, 0, 0, 0);
        sII = __builtin_amdgcn_mfma_f32_16x16x32_f16(q1, bKi, sII, 0, 0, 0);
        sRI = __builtin_amdgcn_mfma_f32_16x16x32_f16(q0, bKi, sRI, 0, 0, 0);
        sIR = __builtin_amdgcn_mfma_f32_16x16x32_f16(q1, bKr, sIR, 0, 0, 0);
      }
      {  // ec == 8 (Q fragment in registers)
        f16x8 bKr = *(const f16x8*)(Kpack + kb0 + (size_t)8 * 512 + L * 8);
        f16x8 bKi = *(const f16x8*)(Kpack + kb1 + (size_t)8 * 512 + L * 8);
        sRR = __builtin_amdgcn_mfma_f32_16x16x32_f16(Qf8[0], bKr, sRR, 0, 0, 0);
        sII = __builtin_amdgcn_mfma_f32_16x16x32_f16(Qf8[1], bKi, sII, 0, 0, 0);
        sRI = __builtin_amdgcn_mfma_f32_16x16x32_f16(Qf8[0], bKi, sRI, 0, 0, 0);
        sIR = __builtin_amdgcn_mfma_f32_16x16x32_f16(Qf8[1], bKr, sIR, 0, 0, 0);
      }
      __builtin_amdgcn_s_setprio(0);

      int jj = (jt * 4 + w) * 16 + lc;
      int ksw = jj >> 5, qw = (jj >> 3) & 3, iw = jj & 7;
      int jtile = jt * 4 + w;
#pragma unroll
      for (int r = 0; r < 4; ++r) {
        float vr = sRR[r] - sII[r];
        float vi = sRI[r] + sIR[r];
        _Float16 mlrh = (_Float16)red_max16(vr);
        _Float16 mlih = (_Float16)red_max16(vi);
        float mlr = (float)mlrh;
        float mli = (float)mlih;
        float ur = __expf(vr - mlr);
        float ui = __expf(vi - mli);
        int row = q * 4 + r;
        sP2[0][ksw][qw][row][iw] = (_Float16)ur;
        sP2[1][ksw][qw][row][iw] = (_Float16)ui;
        float sr = red_sum16(ur);
        float si = red_sum16(ui);
        if (lc == 0) {
          sM[0][jtile][row] = mlrh;
          sS[0][jtile][row] = (_Float16)sr;
          sM[1][jtile][row] = mlih;
          sS[1][jtile][row] = (_Float16)si;
        }
      }
    }
    __syncthreads();  // P + stats published

    // ================= stat merge for row lc (conflict-free scalar reads) =======
    float mfR = -3.0e38f, mfI = -3.0e38f;
#pragma unroll
    for (int j = 0; j < 32; ++j) {
      mfR = fmaxf(mfR, (float)sM[0][j][lc]);
      mfI = fmaxf(mfI, (float)sM[1][j][lc]);
    }
    float lR = 0.f, lI = 0.f;
#pragma unroll
    for (int j = 0; j < 32; ++j) {
      lR += (float)sS[0][j][lc] * __expf((float)sM[0][j][lc] - mfR);
      lI += (float)sS[1][j][lc] * __expf((float)sM[1][j][lc] - mfI);
    }
    float gRb = INV_S / lR;
    float gIb = INV_S / lI;

    // ================= PV: pre-normalized A-frags, 2 accs, no barriers =========
    for (int ks = 0; ks < 16; ++ks) {
      int jtA = ks * 2 + h;
      float gR = __expf((float)sM[0][jtA][lc] - mfR) * gRb;
      float gI = __expf((float)sM[1][jtA][lc] - mfI) * gIb;
      f16x8 uR = *(const f16x8*)&sP2[0][ks][q][lc][0];
      f16x8 uI = *(const f16x8*)&sP2[1][ks][q][lc][0];
      _Float16 hR = (_Float16)gR;
      _Float16 hI = (_Float16)gI;
      _Float16 hmI = (_Float16)(-gI);
      f16x8 aR, aI, amI;
#pragma unroll
      for (int i = 0; i < 8; ++i) {
        aR[i] = uR[i] * hR;
        aI[i] = uI[i] * hI;
        amI[i] = uI[i] * hmI;
      }
      __builtin_amdgcn_s_setprio(1);
#pragma unroll
      for (int ti = 0; ti < 5; ++ti) {
        if (ti < nt) {
          int et = t0 + ti;
          size_t vb = (((size_t)(b * 2 + 0) * 17 + et) * 16 + ks) * 512;
          size_t vb2 = (((size_t)(b * 2 + 1) * 17 + et) * 16 + ks) * 512;
          f16x8 bVr = *(const f16x8*)(Vpack + vb + L * 8);
          f16x8 bVi = *(const f16x8*)(Vpack + vb2 + L * 8);
          accR[ti] = __builtin_amdgcn_mfma_f32_16x16x32_f16(aR, bVr, accR[ti], 0, 0, 0);
          accR[ti] = __builtin_amdgcn_mfma_f32_16x16x32_f16(amI, bVi, accR[ti], 0, 0, 0);
          accI[ti] = __builtin_amdgcn_mfma_f32_16x16x32_f16(aR, bVi, accI[ti], 0, 0, 0);
          accI[ti] = __builtin_amdgcn_mfma_f32_16x16x32_f16(aI, bVr, accI[ti], 0, 0, 0);
        }
      }
      __builtin_amdgcn_s_setprio(0);
    }
    __syncthreads();  // sP2/sM/sS reused by next pass's phase 1
  }

  // ---- store OXh f16 rows into LHf[.][528..1056) ----
  _Float16* obase = OXh + (size_t)(b * 512 + rt * 16) * LD16 + OXOFF;
#pragma unroll
  for (int ti = 0; ti < 5; ++ti) {
    if (ti < nt) {
      int e = (t0 + ti) * 16 + lc;
      if (e < 257) {
#pragma unroll
        for (int r = 0; r < 4; ++r) {
          _Float16* dst = obase + (size_t)(q * 4 + r) * LD16;
          dst[e] = (_Float16)accR[ti][r];
          dst[264 + e] = (_Float16)accI[ti][r];
        }
      }
    }
  }
}

// ---------------- MFMA f16 GEMM: out = OXh @ iDt ----------------

__global__ __launch_bounds__(256) void gemm_irfft(
    const _Float16* __restrict__ LHf, const _Float16* __restrict__ iDt,
    float* __restrict__ out) {
  __shared__ __align__(16) char lds[33792];
  _Float16* As = (_Float16*)lds;              // [128][40]
  _Float16* Bs = (_Float16*)(lds + 10240);    // [64][40]
  float* CL = (float*)lds;                    // [128][66]

  int t = threadIdx.x;
  int w = t >> 6, L = t & 63, q = L >> 4, lc = L & 15;
  int row0 = blockIdx.y * 128;
  int n0 = blockIdx.x * 64;

  const f16x8 zero8 = {(_Float16)0, (_Float16)0, (_Float16)0, (_Float16)0,
                       (_Float16)0, (_Float16)0, (_Float16)0, (_Float16)0};

  f32x4 acc[2][4];
#pragma unroll
  for (int i = 0; i < 2; ++i)
#pragma unroll
    for (int j = 0; j < 4; ++j) acc[i][j] = f32x4{0.f, 0.f, 0.f, 0.f};

  for (int k0 = 0; k0 < 544; k0 += 32) {
    {
      int m = t >> 1, half = t & 1;
      int kk = k0 + half * 16;
      f16x8 h0, h1;
      if (kk < 528) {
        const _Float16* src = LHf + (size_t)(row0 + m) * LD16 + OXOFF + kk;
        h0 = *(const f16x8*)(src);
        h1 = *(const f16x8*)(src + 8);
      } else {
        h0 = zero8; h1 = zero8;
      }
      *(f16x8*)(As + m * 40 + half * 16) = h0;
      *(f16x8*)(As + m * 40 + half * 16 + 8) = h1;
    }
    {
      int row = t >> 2, ch = t & 3;
      f16x8 bv = *(const f16x8*)(iDt + (size_t)(n0 + row) * 544 + k0 + ch * 8);
      *(f16x8*)(Bs + row * 40 + ch * 8) = bv;
    }
    __syncthreads();
#pragma unroll
    for (int sub = 0; sub < 2; ++sub) {
      f16x8 af = *(const f16x8*)(As + (w * 32 + sub * 16 + lc) * 40 + q * 8);
#pragma unroll
      for (int ns = 0; ns < 4; ++ns) {
        f16x8 bf = *(const f16x8*)(Bs + (ns * 16 + lc) * 40 + q * 8);
        acc[sub][ns] = __builtin_amdgcn_mfma_f32_16x16x32_f16(af, bf, acc[sub][ns], 0, 0, 0);
      }
    }
    __syncthreads();
  }

#pragma unroll
  for (int sub = 0; sub < 2; ++sub)
#pragma unroll
    for (int ns = 0; ns < 4; ++ns)
#pragma unroll
      for (int r = 0; r < 4; ++r)
        CL[(w * 32 + sub * 16 + q * 4 + r) * 66 + ns * 16 + lc] = acc[sub][ns][r];
  __syncthreads();

#pragma unroll
  for (int rep = 0; rep < 8; ++rep) {
    int idx = rep * 256 + t;
    int row = idx >> 4;
    int c4 = idx & 15;
    f32x4 v = *(const f32x4*)(CL + row * 66 + c4 * 4);
    float4 o = {v[0], v[1], v[2], v[3]};
    *(float4*)(out + (size_t)(row0 + row) * 512 + n0 + c4 * 4) = o;
  }
}

// ---------------- launch ----------------

extern "C" void kernel_launch(void* const* d_in, const int* in_sizes, int n_in,
                              void* d_out, int out_size, void* d_ws, size_t ws_size,
                              hipStream_t stream) {
  const float* x   = (const float*)d_in[0];
  const float* l1r = (const float*)d_in[1];
  const float* l1i = (const float*)d_in[2];
  const float* h1r = (const float*)d_in[3];
  const float* h1i = (const float*)d_in[4];
  const float* lbr = (const float*)d_in[5];
  const float* lbi = (const float*)d_in[6];
  const float* hbr = (const float*)d_in[7];
  const float* hbi = (const float*)d_in[8];
  float* out = (float*)d_out;

  _Float16* ws = (_Float16*)d_ws;
  size_t off = 0;
  _Float16* LHf = ws + off;   off += (size_t)32768 * LD16;        // 69.2 MB
  _Float16* Kpack = ws + off; off += (size_t)73728 * 512;         // 75.5 MB
  _Float16* Vpack = ws + off; off += (size_t)64 * 2 * 17 * 16 * 512;  // 35.7 MB
  _Float16* Wt = ws + off;    off += (size_t)1088 * 512;          // 1.1 MB
  _Float16* iDt = ws + off;   off += (size_t)512 * 544;           // 0.6 MB

  hipMemsetAsync(LHf, 0, (size_t)32768 * LD16 * 2, stream);

  build_W<<<1088, 256, 0, stream>>>(l1r, l1i, h1r, h1i, Wt);
  build_idt<<<(512 * 544 + 255) / 256, 256, 0, stream>>>(iDt);

  gemm_main<<<dim3(17, 256), 256, 0, stream>>>(x, Wt, lbr, lbi, hbr, hbi, LHf);
  repack_K<<<73728 / 4, 256, 0, stream>>>(LHf, Kpack);
  repack_V<<<64 * 2 * 17, 256, 0, stream>>>(LHf, Vpack);
  attn_mfma3<<<2048, 256, 0, stream>>>(LHf, Kpack, Vpack, LHf);
  gemm_irfft<<<dim3(8, 256), 256, 0, stream>>>(LHf, iDt, out);
}

// Round 9
// 604.633 us; speedup vs baseline: 1.5651x; 1.2139x over previous
//
#include <hip/hip_runtime.h>
#include <math.h>

// B=64, C=512, S=512, E=257, LK=128, HK=129.
// high_x is dead code in the reference: only low_x = attn(low,low,low)+attn(low,high,low).
//
// Pipeline (all heavy math on MFMA f16):
//  1. xcast: X f32 -> Xh f16 (aliases Kpack region; consumed by gemm_main before repack_K)
//  2. build_W: Wt[c][n] f16 = combined rfft+projection weight (512 -> 1028, pad 1152)
//  3. build_idt: iDt[n][k] f16 = irfft matrix matching OXh row layout [re264|im264]
//  4. gemm_main (MFMA f16): LHf = relu(x @ W + bias) * S_FOLD.
//     128x128 tile, BK=32, register-staged f16x8 LDS staging (NOT global_load_lds:
//     that builtin is the prime suspect for the round-7/8 container deaths).
//  5. repack_K: LHf -> Kpack in exact MFMA B-frag order (coalesced attention loads)
//  6. repack_V: LHf low -> Vpack (LDS transpose) in PV B-frag order
//  7. attn (MFMA f16 flash, DEFERRED PV): Q in chunk-linear LDS, P lane-linear,
//     f16 stats stride-18, 3 blocks/CU. (verified 280us structure, unchanged)
//  8. gemm_irfft (MFMA f16): out = OXh @ iDt. 128x128, K=544, register staging
//     with zero-padded tail step (OXh row ends at col 528).
//
// ws: LHf 69.2 MB + Kpack 75.5 MB (Xh alias) + Vpack 35.7 MB + Wt 1.2 MB + iDt 0.6 MB.

#define LD16 1056   // halves per LHf row: [lr 264 | li 264 | hr 264 | hi 264]
#define OXOFF 528   // OXh f16 output written into LHf[row][528..1056): [re 264 | im 264]

typedef __attribute__((ext_vector_type(4))) _Float16 f16x4;
typedef __attribute__((ext_vector_type(8))) _Float16 f16x8;
typedef __attribute__((ext_vector_type(4))) float f32x4;

#define S_FOLD 0.24975653f    // sqrt(1/sqrt(257))
#define INV_S  4.0039005f     // 1/S_FOLD
#define SC512  0.0441941738241592f   // 1/sqrt(512)

// ---------------- X f32 -> f16 ----------------

__global__ __launch_bounds__(256) void xcast(
    const float* __restrict__ X, _Float16* __restrict__ Xh) {
  const size_t total = (size_t)32768 * 512;
  size_t stride = (size_t)gridDim.x * 256 * 8;
  for (size_t idx = ((size_t)blockIdx.x * 256 + threadIdx.x) * 8; idx < total;
       idx += stride) {
    float4 a0 = *(const float4*)(X + idx);
    float4 a1 = *(const float4*)(X + idx + 4);
    f16x8 h = {(_Float16)a0.x, (_Float16)a0.y, (_Float16)a0.z, (_Float16)a0.w,
               (_Float16)a1.x, (_Float16)a1.y, (_Float16)a1.z, (_Float16)a1.w};
    *(f16x8*)(Xh + idx) = h;
  }
}

// ---------------- build combined rfft+projection weight, B-transposed ----------------
// Wt[c][n], c in [0,1152), n in [0,512). c>=1028 -> 0.

__global__ __launch_bounds__(256) void build_W(
    const float* __restrict__ l1r, const float* __restrict__ l1i,
    const float* __restrict__ h1r, const float* __restrict__ h1i,
    _Float16* __restrict__ Wt) {
  int c = blockIdx.x;
  int t = threadIdx.x;
  if (c >= 1028) {
    for (int n = t; n < 512; n += 256) Wt[(size_t)c * 512 + n] = (_Float16)0.0f;
    return;
  }
  __shared__ float Tc[512], Ts[512];
  __shared__ float wr[132], wi[132];
  for (int i = t; i < 512; i += 256) {
    float ang = (float)i * 0.0122718463030851f;  // 2*pi/512
    Tc[i] = cosf(ang);
    Ts[i] = sinf(ang);
  }
  int sub = (c >= 771) ? 3 : (c >= 514) ? 2 : (c >= 257) ? 1 : 0;
  int e = c - sub * 257;
  int Kn = (sub < 2) ? 128 : 129;
  int kb = (sub < 2) ? 0 : 128;
  if (t < Kn) {
    if (sub < 2) { wr[t] = l1r[t * 257 + e]; wi[t] = l1i[t * 257 + e]; }
    else         { wr[t] = h1r[t * 257 + e]; wi[t] = h1i[t * 257 + e]; }
  }
  __syncthreads();
  bool imag_out = (sub & 1);
  for (int n = t; n < 512; n += 256) {
    float acc = 0.f;
    for (int k = 0; k < Kn; ++k) {
      int kk = kb + k;
      int m = (n * kk) & 511;
      float Fr = Tc[m] * SC512;
      float Fi = -Ts[m] * SC512;
      if (!imag_out) acc += Fr * wr[k] - Fi * wi[k];
      else           acc += Fr * wi[k] + Fi * wr[k];
    }
    Wt[(size_t)c * 512 + n] = (_Float16)acc;
  }
}

// ---------------- build irfft matrix, B-transposed, matching OXh layout ----------------

__global__ __launch_bounds__(256) void build_idt(_Float16* __restrict__ iDt) {
  int idx = blockIdx.x * 256 + threadIdx.x;
  const int total = 512 * 544;
  if (idx >= total) return;
  int n = idx / 544;
  int k = idx - n * 544;
  float val = 0.f;
  if (k < 264) {
    int e = k;
    if (e <= 256) {
      float ce = (e == 0 || e == 256) ? 1.f : 2.f;
      int m = (n * e) & 511;
      val = ce * SC512 * cosf((float)m * 0.0122718463030851f);
    }
  } else if (k < 528) {
    int e = k - 264;
    if (e <= 256) {
      float ce = (e == 0 || e == 256) ? 1.f : 2.f;
      int m = (n * e) & 511;
      val = -ce * SC512 * sinf((float)m * 0.0122718463030851f);
    }
  }
  iDt[(size_t)n * 544 + k] = (_Float16)val;
}

// ---------------- MFMA f16 GEMM: LHf = relu(Xh @ W + bias) * S_FOLD ----------------
// M=32768, N=1152 (9 tiles of 128, c>=1028 discarded), K=512, BK=32.
// Block 256 (4 waves, 2x2); wave owns 64x64. Register-staged f16x8 LDS staging.

__global__ __launch_bounds__(256) void gemm_main(
    const _Float16* __restrict__ Xh, const _Float16* __restrict__ Wt,
    const float* __restrict__ lbr, const float* __restrict__ lbi,
    const float* __restrict__ hbr, const float* __restrict__ hbi,
    _Float16* __restrict__ LHf) {
  __shared__ __align__(16) _Float16 As[128 * 32];
  __shared__ __align__(16) _Float16 Bs[128 * 32];

  int t = threadIdx.x;
  int w = t >> 6, L = t & 63, q = L >> 4, lc = L & 15;
  int wr = w >> 1, wc = w & 1;
  int row0 = blockIdx.y * 128;
  int n0 = blockIdx.x * 128;

  int sr = t >> 2, sc = (t & 3) * 8;  // staging: row 0..63, col 0/8/16/24

  f32x4 acc[4][4];
#pragma unroll
  for (int i = 0; i < 4; ++i)
#pragma unroll
    for (int j = 0; j < 4; ++j) acc[i][j] = f32x4{0.f, 0.f, 0.f, 0.f};

  for (int k0 = 0; k0 < 512; k0 += 32) {
    // stage A/B: 128 rows x 32 halves each, f16x8 per lane, 2 rows apart by 64
    f16x8 a0 = *(const f16x8*)(Xh + (size_t)(row0 + sr) * 512 + k0 + sc);
    f16x8 a1 = *(const f16x8*)(Xh + (size_t)(row0 + sr + 64) * 512 + k0 + sc);
    f16x8 b0 = *(const f16x8*)(Wt + (size_t)(n0 + sr) * 512 + k0 + sc);
    f16x8 b1 = *(const f16x8*)(Wt + (size_t)(n0 + sr + 64) * 512 + k0 + sc);
    *(f16x8*)(As + sr * 32 + sc) = a0;
    *(f16x8*)(As + (sr + 64) * 32 + sc) = a1;
    *(f16x8*)(Bs + sr * 32 + sc) = b0;
    *(f16x8*)(Bs + (sr + 64) * 32 + sc) = b1;
    __syncthreads();

    f16x8 af[4], bf[4];
#pragma unroll
    for (int m = 0; m < 4; ++m)
      af[m] = *(const f16x8*)(As + (wr * 64 + m * 16 + lc) * 32 + q * 8);
#pragma unroll
    for (int n = 0; n < 4; ++n)
      bf[n] = *(const f16x8*)(Bs + (wc * 64 + n * 16 + lc) * 32 + q * 8);
#pragma unroll
    for (int m = 0; m < 4; ++m)
#pragma unroll
      for (int n = 0; n < 4; ++n)
        acc[m][n] = __builtin_amdgcn_mfma_f32_16x16x32_f16(af[m], bf[n], acc[m][n], 0, 0, 0);
    __syncthreads();
  }

  // epilogue: direct scalar f16 writes with bias+relu+scale (c<1028 guard)
#pragma unroll
  for (int m = 0; m < 4; ++m) {
#pragma unroll
    for (int ns = 0; ns < 4; ++ns) {
      int c = n0 + wc * 64 + ns * 16 + lc;
      if (c < 1028) {
        int sub = (c >= 771) ? 3 : (c >= 514) ? 2 : (c >= 257) ? 1 : 0;
        int e = c - sub * 257;
        float bv = (sub == 0) ? lbr[e] : (sub == 1) ? lbi[e] : (sub == 2) ? hbr[e] : hbi[e];
#pragma unroll
        for (int r = 0; r < 4; ++r) {
          int row = row0 + wr * 64 + m * 16 + q * 4 + r;
          float val = fmaxf(acc[m][ns][r] + bv, 0.f) * S_FOLD;
          LHf[(size_t)row * LD16 + sub * 264 + e] = (_Float16)val;
        }
      }
    }
  }
}

// ---------------- repack K into MFMA B-frag-linear order ----------------

__global__ __launch_bounds__(256) void repack_K(
    const _Float16* __restrict__ LHf, _Float16* __restrict__ Kpack) {
  int t = threadIdx.x;
  int w = t >> 6, L = t & 63, q = L >> 4, lc = L & 15;
  int wc = blockIdx.x * 4 + w;
  int ec = wc % 9;
  int tmp = wc / 9;
  int jt = tmp & 31; tmp >>= 5;
  int comp = tmp & 1; tmp >>= 1;
  int pass = tmp & 1;
  int b = tmp >> 1;
  f16x8 v;
  if (ec == 8 && q > 0) {
    v = f16x8{(_Float16)0, (_Float16)0, (_Float16)0, (_Float16)0,
              (_Float16)0, (_Float16)0, (_Float16)0, (_Float16)0};
  } else {
    v = *(const f16x8*)(LHf + (size_t)(b * 512 + jt * 16 + lc) * LD16 +
                        pass * 528 + comp * 264 + ec * 32 + q * 8);
  }
  *(f16x8*)(Kpack + (size_t)wc * 512 + L * 8) = v;
}

// ---------------- repack V (low) into PV B-frag order via LDS transpose ----------------

__global__ __launch_bounds__(256) void repack_V(
    const _Float16* __restrict__ LHf, _Float16* __restrict__ Vpack) {
  int bid = blockIdx.x;
  int et = bid % 17;
  int tmp = bid / 17;
  int comp = tmp & 1;
  int b = tmp >> 1;
  int t = threadIdx.x;
  __shared__ __align__(16) _Float16 tile[512 * 16];

  const f16x8 zero8 = {(_Float16)0, (_Float16)0, (_Float16)0, (_Float16)0,
                       (_Float16)0, (_Float16)0, (_Float16)0, (_Float16)0};
  for (int j = t; j < 512; j += 256) {
    const _Float16* src = LHf + (size_t)(b * 512 + j) * LD16 + comp * 264 + et * 16;
    f16x8 v0, v1;
    if (et < 16) {
      v0 = *(const f16x8*)(src);
      v1 = *(const f16x8*)(src + 8);
    } else {
      v0 = *(const f16x8*)(src);
      v1 = zero8;
    }
    *(f16x8*)(tile + j * 16) = v0;
    *(f16x8*)(tile + j * 16 + 8) = v1;
  }
  __syncthreads();

#pragma unroll
  for (int it = 0; it < 4; ++it) {
    int c2 = it * 256 + t;
    int ks = c2 >> 6;
    int L2 = c2 & 63;
    int q2 = L2 >> 4, lc2 = L2 & 15;
    f16x8 v;
#pragma unroll
    for (int i = 0; i < 8; ++i) v[i] = tile[(ks * 32 + q2 * 8 + i) * 16 + lc2];
    *(f16x8*)(Vpack + ((((size_t)(b * 2 + comp) * 17 + et) * 16 + ks) * 512) + L2 * 8) = v;
  }
}

// ---------------- DPP 16-lane reductions (VALU pipe, no DS latency) ----------------

template <int CTRL>
__device__ __forceinline__ float dpp_f32(float x) {
  return __int_as_float(
      __builtin_amdgcn_update_dpp(0, __float_as_int(x), CTRL, 0xF, 0xF, true));
}

__device__ __forceinline__ float red_max16(float x) {
  x = fmaxf(x, dpp_f32<0xB1>(x));
  x = fmaxf(x, dpp_f32<0x4E>(x));
  x = fmaxf(x, dpp_f32<0x141>(x));
  x = fmaxf(x, dpp_f32<0x140>(x));
  return x;
}

__device__ __forceinline__ float red_sum16(float x) {
  x += dpp_f32<0xB1>(x);
  x += dpp_f32<0x4E>(x);
  x += dpp_f32<0x141>(x);
  x += dpp_f32<0x140>(x);
  return x;
}

// ---------------- MFMA f16 flash attention, DEFERRED PV, 3 blocks/CU ----------------
// (round-6 verified structure, unchanged: 280us, MfmaUtil 22%, Occ 30%, conflicts 2e6)

__global__ __launch_bounds__(256, 3) void attn_mfma3(
    const _Float16* __restrict__ LHf, const _Float16* __restrict__ Kpack,
    const _Float16* __restrict__ Vpack, _Float16* __restrict__ OXh) {
  int bid = blockIdx.x;
  int xcd = bid & 7;
  int ix = bid >> 3;
  int rt = ix & 31;
  int b = xcd + 8 * (ix >> 5);
  int t = threadIdx.x;
  int w = t >> 6, L = t & 63, q = L >> 4, lc = L & 15;

  __shared__ __align__(16) _Float16 sQc[2][8][64][8];      // 16384 B
  __shared__ __align__(16) _Float16 sP2[2][16][4][16][8];  // 32768 B
  __shared__ __align__(16) _Float16 sM[2][32][18];         // 2304 B
  __shared__ __align__(16) _Float16 sS[2][32][18];         // 2304 B

  const f16x8 zero8 = {(_Float16)0, (_Float16)0, (_Float16)0, (_Float16)0,
                       (_Float16)0, (_Float16)0, (_Float16)0, (_Float16)0};

  // fill sQc (chunk-linear: lane L owns slot [comp][ec][L]) + Qf8 in regs
  const _Float16* qbase = LHf + (size_t)(b * 512 + rt * 16 + lc) * LD16;
  f16x8 Qf8[2];
#pragma unroll
  for (int comp = 0; comp < 2; ++comp)
    Qf8[comp] = (q == 0) ? *(const f16x8*)(qbase + comp * 264 + 256) : zero8;
  for (int g = w; g < 16; g += 4) {
    int comp = g >> 3, ec = g & 7;
    f16x8 v = *(const f16x8*)(qbase + comp * 264 + ec * 32 + q * 8);
    *(f16x8*)(&sQc[comp][ec][L][0]) = v;
  }
  __syncthreads();

  int t0 = (w == 0) ? 0 : (4 * w + 1);   // et tiles {0..4},{5..8},{9..12},{13..16}
  int nt = (w == 0) ? 5 : 4;
  int h = q >> 1;

  f32x4 accR[5], accI[5];  // final normalized outputs, accumulated across passes
#pragma unroll
  for (int i = 0; i < 5; ++i) {
    accR[i] = f32x4{0.f, 0.f, 0.f, 0.f};
    accI[i] = f32x4{0.f, 0.f, 0.f, 0.f};
  }

  for (int pass = 0; pass < 2; ++pass) {
    // ================= phase 1: QK + local softmax, no barriers =================
    for (int jt = 0; jt < 8; ++jt) {
      size_t kb0 = ((((size_t)(b * 2 + pass) * 2 + 0) * 32 + (jt * 4 + w)) * 9) * 512;
      size_t kb1 = ((((size_t)(b * 2 + pass) * 2 + 1) * 32 + (jt * 4 + w)) * 9) * 512;
      f32x4 sRR = f32x4{0.f, 0.f, 0.f, 0.f};
      f32x4 sII = f32x4{0.f, 0.f, 0.f, 0.f};
      f32x4 sRI = f32x4{0.f, 0.f, 0.f, 0.f};
      f32x4 sIR = f32x4{0.f, 0.f, 0.f, 0.f};
      __builtin_amdgcn_s_setprio(1);
#pragma unroll
      for (int ec = 0; ec < 8; ++ec) {
        f16x8 bKr = *(const f16x8*)(Kpack + kb0 + (size_t)ec * 512 + L * 8);
        f16x8 bKi = *(const f16x8*)(Kpack + kb1 + (size_t)ec * 512 + L * 8);
        f16x8 q0 = *(const f16x8*)(&sQc[0][ec][L][0]);
        f16x8 q1 = *(const f16x8*)(&sQc[1][ec][L][0]);
        sRR = __builtin_amdgcn_mfma_f32_16x16x32_f16(q0, bKr, sRR, 0, 0, 0);
        sII = __builtin_amdgcn_mfma_f32_16x16x32_f16(q1, bKi, sII, 0, 0, 0);
        sRI = __builtin_amdgcn_mfma_f32_16x16x32_f16(q0, bKi, sRI, 0, 0, 0);
        sIR = __builtin_amdgcn_mfma_f32_16x16x32_f16(q1, bKr, sIR, 0, 0, 0);
      }
      {  // ec == 8 (Q fragment in registers)
        f16x8 bKr = *(const f16x8*)(Kpack + kb0 + (size_t)8 * 512 + L * 8);
        f16x8 bKi = *(const f16x8*)(Kpack + kb1 + (size_t)8 * 512 + L * 8);
        sRR = __builtin_amdgcn_mfma_f32_16x16x32_f16(Qf8[0], bKr, sRR, 0, 0, 0);
        sII = __builtin_amdgcn_mfma_f32_16x16x32_f16(Qf8[1], bKi, sII, 0, 0, 0);
        sRI = __builtin_amdgcn_mfma_f32_16x16x32_f16(Qf8[0], bKi, sRI, 0, 0, 0);
        sIR = __builtin_amdgcn_mfma_f32_16x16x32_f16(Qf8[1], bKr, sIR, 0, 0, 0);
      }
      __builtin_amdgcn_s_setprio(0);

      int jj = (jt * 4 + w) * 16 + lc;
      int ksw = jj >> 5, qw = (jj >> 3) & 3, iw = jj & 7;
      int jtile = jt * 4 + w;
#pragma unroll
      for (int r = 0; r < 4; ++r) {
        float vr = sRR[r] - sII[r];
        float vi = sRI[r] + sIR[r];
        _Float16 mlrh = (_Float16)red_max16(vr);
        _Float16 mlih = (_Float16)red_max16(vi);
        float mlr = (float)mlrh;
        float mli = (float)mlih;
        float ur = __expf(vr - mlr);
        float ui = __expf(vi - mli);
        int row = q * 4 + r;
        sP2[0][ksw][qw][row][iw] = (_Float16)ur;
        sP2[1][ksw][qw][row][iw] = (_Float16)ui;
        float sr = red_sum16(ur);
        float si = red_sum16(ui);
        if (lc == 0) {
          sM[0][jtile][row] = mlrh;
          sS[0][jtile][row] = (_Float16)sr;
          sM[1][jtile][row] = mlih;
          sS[1][jtile][row] = (_Float16)si;
        }
      }
    }
    __syncthreads();  // P + stats published

    // ================= stat merge for row lc (conflict-free scalar reads) =======
    float mfR = -3.0e38f, mfI = -3.0e38f;
#pragma unroll
    for (int j = 0; j < 32; ++j) {
      mfR = fmaxf(mfR, (float)sM[0][j][lc]);
      mfI = fmaxf(mfI, (float)sM[1][j][lc]);
    }
    float lR = 0.f, lI = 0.f;
#pragma unroll
    for (int j = 0; j < 32; ++j) {
      lR += (float)sS[0][j][lc] * __expf((float)sM[0][j][lc] - mfR);
      lI += (float)sS[1][j][lc] * __expf((float)sM[1][j][lc] - mfI);
    }
    float gRb = INV_S / lR;
    float gIb = INV_S / lI;

    // ================= PV: pre-normalized A-frags, 2 accs, no barriers =========
    for (int ks = 0; ks < 16; ++ks) {
      int jtA = ks * 2 + h;
      float gR = __expf((float)sM[0][jtA][lc] - mfR) * gRb;
      float gI = __expf((float)sM[1][jtA][lc] - mfI) * gIb;
      f16x8 uR = *(const f16x8*)&sP2[0][ks][q][lc][0];
      f16x8 uI = *(const f16x8*)&sP2[1][ks][q][lc][0];
      _Float16 hR = (_Float16)gR;
      _Float16 hI = (_Float16)gI;
      _Float16 hmI = (_Float16)(-gI);
      f16x8 aR, aI, amI;
#pragma unroll
      for (int i = 0; i < 8; ++i) {
        aR[i] = uR[i] * hR;
        aI[i] = uI[i] * hI;
        amI[i] = uI[i] * hmI;
      }
      __builtin_amdgcn_s_setprio(1);
#pragma unroll
      for (int ti = 0; ti < 5; ++ti) {
        if (ti < nt) {
          int et = t0 + ti;
          size_t vb = (((size_t)(b * 2 + 0) * 17 + et) * 16 + ks) * 512;
          size_t vb2 = (((size_t)(b * 2 + 1) * 17 + et) * 16 + ks) * 512;
          f16x8 bVr = *(const f16x8*)(Vpack + vb + L * 8);
          f16x8 bVi = *(const f16x8*)(Vpack + vb2 + L * 8);
          accR[ti] = __builtin_amdgcn_mfma_f32_16x16x32_f16(aR, bVr, accR[ti], 0, 0, 0);
          accR[ti] = __builtin_amdgcn_mfma_f32_16x16x32_f16(amI, bVi, accR[ti], 0, 0, 0);
          accI[ti] = __builtin_amdgcn_mfma_f32_16x16x32_f16(aR, bVi, accI[ti], 0, 0, 0);
          accI[ti] = __builtin_amdgcn_mfma_f32_16x16x32_f16(aI, bVr, accI[ti], 0, 0, 0);
        }
      }
      __builtin_amdgcn_s_setprio(0);
    }
    __syncthreads();  // sP2/sM/sS reused by next pass's phase 1
  }

  // ---- store OXh f16 rows into LHf[.][528..1056) ----
  _Float16* obase = OXh + (size_t)(b * 512 + rt * 16) * LD16 + OXOFF;
#pragma unroll
  for (int ti = 0; ti < 5; ++ti) {
    if (ti < nt) {
      int e = (t0 + ti) * 16 + lc;
      if (e < 257) {
#pragma unroll
        for (int r = 0; r < 4; ++r) {
          _Float16* dst = obase + (size_t)(q * 4 + r) * LD16;
          dst[e] = (_Float16)accR[ti][r];
          dst[264 + e] = (_Float16)accI[ti][r];
        }
      }
    }
  }
}

// ---------------- MFMA f16 GEMM: out = OXh @ iDt ----------------
// M=32768, N=512 (4 tiles of 128), K=544 (OXh pad). Register-staged f16x8;
// zero-padded tail for cols 528..543.

__global__ __launch_bounds__(256) void gemm_irfft(
    const _Float16* __restrict__ LHf, const _Float16* __restrict__ iDt,
    float* __restrict__ out) {
  __shared__ __align__(16) _Float16 As[128 * 32];
  __shared__ __align__(16) _Float16 Bs[128 * 32];

  int t = threadIdx.x;
  int w = t >> 6, L = t & 63, q = L >> 4, lc = L & 15;
  int wr = w >> 1, wc = w & 1;
  int row0 = blockIdx.y * 128;
  int n0 = blockIdx.x * 128;

  int sr = t >> 2, sc = (t & 3) * 8;

  const f16x8 zero8 = {(_Float16)0, (_Float16)0, (_Float16)0, (_Float16)0,
                       (_Float16)0, (_Float16)0, (_Float16)0, (_Float16)0};

  f32x4 acc[4][4];
#pragma unroll
  for (int i = 0; i < 4; ++i)
#pragma unroll
    for (int j = 0; j < 4; ++j) acc[i][j] = f32x4{0.f, 0.f, 0.f, 0.f};

  for (int k0 = 0; k0 < 544; k0 += 32) {
    // A: OXh rows, valid cols < 528 (tail cols 528..543 zero-padded)
    f16x8 a0, a1;
    if (k0 + sc < 528) {
      a0 = *(const f16x8*)(LHf + (size_t)(row0 + sr) * LD16 + OXOFF + k0 + sc);
      a1 = *(const f16x8*)(LHf + (size_t)(row0 + sr + 64) * LD16 + OXOFF + k0 + sc);
    } else {
      a0 = zero8; a1 = zero8;
    }
    f16x8 b0 = *(const f16x8*)(iDt + (size_t)(n0 + sr) * 544 + k0 + sc);
    f16x8 b1 = *(const f16x8*)(iDt + (size_t)(n0 + sr + 64) * 544 + k0 + sc);
    *(f16x8*)(As + sr * 32 + sc) = a0;
    *(f16x8*)(As + (sr + 64) * 32 + sc) = a1;
    *(f16x8*)(Bs + sr * 32 + sc) = b0;
    *(f16x8*)(Bs + (sr + 64) * 32 + sc) = b1;
    __syncthreads();

    f16x8 af[4], bf[4];
#pragma unroll
    for (int m = 0; m < 4; ++m)
      af[m] = *(const f16x8*)(As + (wr * 64 + m * 16 + lc) * 32 + q * 8);
#pragma unroll
    for (int n = 0; n < 4; ++n)
      bf[n] = *(const f16x8*)(Bs + (wc * 64 + n * 16 + lc) * 32 + q * 8);
#pragma unroll
    for (int m = 0; m < 4; ++m)
#pragma unroll
      for (int n = 0; n < 4; ++n)
        acc[m][n] = __builtin_amdgcn_mfma_f32_16x16x32_f16(af[m], bf[n], acc[m][n], 0, 0, 0);
    __syncthreads();
  }

#pragma unroll
  for (int m = 0; m < 4; ++m)
#pragma unroll
    for (int ns = 0; ns < 4; ++ns) {
      int c = n0 + wc * 64 + ns * 16 + lc;
#pragma unroll
      for (int r = 0; r < 4; ++r) {
        int row = row0 + wr * 64 + m * 16 + q * 4 + r;
        out[(size_t)row * 512 + c] = acc[m][ns][r];
      }
    }
}

// ---------------- launch ----------------

extern "C" void kernel_launch(void* const* d_in, const int* in_sizes, int n_in,
                              void* d_out, int out_size, void* d_ws, size_t ws_size,
                              hipStream_t stream) {
  const float* x   = (const float*)d_in[0];
  const float* l1r = (const float*)d_in[1];
  const float* l1i = (const float*)d_in[2];
  const float* h1r = (const float*)d_in[3];
  const float* h1i = (const float*)d_in[4];
  const float* lbr = (const float*)d_in[5];
  const float* lbi = (const float*)d_in[6];
  const float* hbr = (const float*)d_in[7];
  const float* hbi = (const float*)d_in[8];
  float* out = (float*)d_out;

  _Float16* ws = (_Float16*)d_ws;
  size_t off = 0;
  _Float16* LHf = ws + off;   off += (size_t)32768 * LD16;        // 69.2 MB
  _Float16* Kpack = ws + off; off += (size_t)73728 * 512;         // 75.5 MB
  _Float16* Vpack = ws + off; off += (size_t)64 * 2 * 17 * 16 * 512;  // 35.7 MB
  _Float16* Wt = ws + off;    off += (size_t)1152 * 512;          // 1.2 MB
  _Float16* iDt = ws + off;   off += (size_t)512 * 544;           // 0.6 MB
  _Float16* Xh = Kpack;  // alias: consumed by gemm_main before repack_K overwrites

  hipMemsetAsync(LHf, 0, (size_t)32768 * LD16 * 2, stream);

  xcast<<<2048, 256, 0, stream>>>(x, Xh);
  build_W<<<1152, 256, 0, stream>>>(l1r, l1i, h1r, h1i, Wt);
  build_idt<<<(512 * 544 + 255) / 256, 256, 0, stream>>>(iDt);

  gemm_main<<<dim3(9, 256), 256, 0, stream>>>(Xh, Wt, lbr, lbi, hbr, hbi, LHf);
  repack_K<<<73728 / 4, 256, 0, stream>>>(LHf, Kpack);
  repack_V<<<64 * 2 * 17, 256, 0, stream>>>(LHf, Vpack);
  attn_mfma3<<<2048, 256, 0, stream>>>(LHf, Kpack, Vpack, LHf);
  gemm_irfft<<<dim3(4, 256), 256, 0, stream>>>(LHf, iDt, out);
}